// Round 6
// baseline (397.015 us; speedup 1.0000x reference)
//
#include <hip/hip_runtime.h>
#include <hip/hip_bf16.h>

#define B_ 2
#define S_ 2048
#define D_ 2048
#define H_ 16
#define HD_ 128

typedef __attribute__((ext_vector_type(4))) float f32x4;
typedef __attribute__((ext_vector_type(8))) short bf16x8;

static __device__ __forceinline__ unsigned short f2bf(float f) {
    unsigned int u = __float_as_uint(f);
    u += 0x7fffu + ((u >> 16) & 1u);
    return (unsigned short)(u >> 16);
}
static __device__ __forceinline__ float bf2f(unsigned short h) {
    return __uint_as_float(((unsigned int)h) << 16);
}

#define MFMA_K32(a, b, c) __builtin_amdgcn_mfma_f32_16x16x32_bf16(a, b, c, 0, 0, 0)

// async global->LDS, 16B per lane. LDS dest is wave-uniform base; HW adds lane*16.
static __device__ __forceinline__ void gll16(const void* g, void* l) {
    __builtin_amdgcn_global_load_lds((const __attribute__((address_space(1))) void*)g,
                                     (__attribute__((address_space(3))) void*)l,
                                     16, 0, 0);
}

// ---------------- fp32 -> bf16 converters ----------------
__global__ void cvt_in(const float4* __restrict__ src, ushort4* __restrict__ dst) {
    int i = blockIdx.x * 256 + threadIdx.x;
    float4 v = src[i];
    ushort4 o;
    o.x = f2bf(v.x); o.y = f2bf(v.y); o.z = f2bf(v.z); o.w = f2bf(v.w);
    dst[i] = o;
}

__global__ void cvt_w4(const float4* __restrict__ s0, ushort4* __restrict__ d0,
                       const float4* __restrict__ s1, ushort4* __restrict__ d1,
                       const float4* __restrict__ s2, ushort4* __restrict__ d2,
                       const float4* __restrict__ s3, ushort4* __restrict__ d3) {
    const float4* s; ushort4* d;
    switch (blockIdx.y) {
        case 0: s = s0; d = d0; break;
        case 1: s = s1; d = d1; break;
        case 2: s = s2; d = d2; break;
        default: s = s3; d = d3; break;
    }
    int i = blockIdx.x * 256 + threadIdx.x;
    float4 v = s[i];
    ushort4 o;
    o.x = f2bf(v.x); o.y = f2bf(v.y); o.z = f2bf(v.z); o.w = f2bf(v.w);
    d[i] = o;
}

// ---------------- GEMM: C[m][n] = sum_k A[m][k] * W[n][k] ----------------
// A bf16 [4096,2048] row-major, W bf16 [2048,2048] row-major.
// Double-buffered LDS, ONE barrier per K-step, pure global_load_lds staging.
// OUT_MODE: 0=bf16 headed [B,H,S,HD]; 1=K attn tiles; 2=V attn tiles; 3=fp32 [M,N].
template<int OUT_MODE>
__global__ __launch_bounds__(256) void gemm_xwt(
        const unsigned short* __restrict__ A,
        const unsigned short* __restrict__ W,
        void* __restrict__ C) {
    constexpr int K = D_;
    __shared__ unsigned short As[2][128 * 32];
    __shared__ unsigned short Ws[2][128 * 32];
    const int tid = threadIdx.x, lane = tid & 63, wid = tid >> 6;
    const int wy = wid >> 1, wx = wid & 1;
    const int g = lane >> 4, lr = lane & 15;
    const int swz = (blockIdx.x & 7) * 64 + (blockIdx.x >> 3);  // XCD swizzle (512%8==0)
    const int bm = (swz & 31) * 128;
    const int bn = (swz >> 5) * 128;

    const int r0 = (wid * 128 + lane) >> 2, c0 = (lane & 3) * 8;  // gll16 chunk map
    const int r1 = r0 + 16;

    f32x4 acc[4][4] = {};

    auto stage = [&](int k0, int nb) {
        gll16(A + (size_t)(bm + r0) * K + k0 + c0, (char*)&As[nb][0] + wid * 2048);
        gll16(A + (size_t)(bm + r1) * K + k0 + c0, (char*)&As[nb][0] + wid * 2048 + 1024);
        gll16(W + (size_t)(bn + r0) * K + k0 + c0, (char*)&Ws[nb][0] + wid * 2048);
        gll16(W + (size_t)(bn + r1) * K + k0 + c0, (char*)&Ws[nb][0] + wid * 2048 + 1024);
    };

    stage(0, 0);  // prologue
    int cur = 0;

    for (int k0 = 0; k0 < K; k0 += 32) {
        __syncthreads();  // drains prefetch: buf[cur] ready; buf[cur^1] free
        if (k0 + 32 < K) stage(k0 + 32, cur ^ 1);
        bf16x8 af[4], wf[4];
        #pragma unroll
        for (int i = 0; i < 4; ++i)
            af[i] = *(const bf16x8*)((const char*)&As[cur][0] + (wy * 64 + i * 16 + lr) * 64 + g * 16);
        #pragma unroll
        for (int i = 0; i < 4; ++i)
            wf[i] = *(const bf16x8*)((const char*)&Ws[cur][0] + (wx * 64 + i * 16 + lr) * 64 + g * 16);
        #pragma unroll
        for (int mi = 0; mi < 4; ++mi)
            #pragma unroll
            for (int ni = 0; ni < 4; ++ni)
                acc[mi][ni] = MFMA_K32(af[mi], wf[ni], acc[mi][ni]);
        cur ^= 1;
    }

    #pragma unroll
    for (int mi = 0; mi < 4; ++mi) {
        #pragma unroll
        for (int ni = 0; ni < 4; ++ni) {
            const int n = bn + wx * 64 + ni * 16 + lr;
            const int m0 = bm + wy * 64 + mi * 16 + g * 4;
            if constexpr (OUT_MODE == 0) {
                #pragma unroll
                for (int rg = 0; rg < 4; ++rg) {
                    int m = m0 + rg;
                    int bb = m >> 11, s = m & (S_ - 1);
                    int hh = n >> 7, dd = n & (HD_ - 1);
                    ((unsigned short*)C)[(((size_t)(bb * H_ + hh) * S_) + s) * HD_ + dd] =
                        f2bf(acc[mi][ni][rg]);
                }
            } else if constexpr (OUT_MODE == 1) {
                #pragma unroll
                for (int rg = 0; rg < 4; ++rg) {
                    int m = m0 + rg;
                    int bb = m >> 11, s = m & (S_ - 1);
                    int hh = n >> 7, dd = n & (HD_ - 1);
                    int vr = s & 63;
                    int pr = (vr & 3) | (((vr >> 3) & 3) << 2) | (((vr >> 2) & 1) << 4) | (vr & 32);
                    size_t eo = ((size_t)(bb * H_ + hh) << 18) + ((size_t)(s >> 6) << 13)
                              + pr * 128 + (((((unsigned)dd) << 1) ^ ((pr & 7) << 4)) >> 1);
                    ((unsigned short*)C)[eo] = f2bf(acc[mi][ni][rg]);
                }
            } else if constexpr (OUT_MODE == 2) {
                int bb = m0 >> 11, s0 = m0 & (S_ - 1);
                int hh = n >> 7, dd = n & (HD_ - 1);
                int ch = ((s0 & 63) >> 3) ^ (dd & 7);
                size_t eo = ((size_t)(bb * H_ + hh) << 18) + ((size_t)(s0 >> 6) << 13)
                          + dd * 64 + (ch << 3) + (s0 & 7);
                ushort4 pk;
                pk.x = f2bf(acc[mi][ni][0]); pk.y = f2bf(acc[mi][ni][1]);
                pk.z = f2bf(acc[mi][ni][2]); pk.w = f2bf(acc[mi][ni][3]);
                *(ushort4*)&((unsigned short*)C)[eo] = pk;
            } else {
                #pragma unroll
                for (int rg = 0; rg < 4; ++rg)
                    ((float*)C)[(size_t)(m0 + rg) * D_ + n] = acc[mi][ni][rg];
            }
        }
    }
}

// ---------------- causal flash attention ----------------
// 512 blocks, one 128-row q-tile each; 4 waves, each wave owns TWO 16-row
// q-groups (A and A+64) so each K/V LDS read feeds 2 MFMAs. Single-buffered
// 32KB LDS (2 blocks/CU). LPT: heaviest q-tiles (largest kv range) dispatch
// first. defer-max softmax (THR=8 in log2 domain), cvt_pk P-pack.
__global__ __launch_bounds__(256) void attn_fwd(
        const unsigned short* __restrict__ Qg,
        const unsigned short* __restrict__ Kt,
        const unsigned short* __restrict__ Vt,
        unsigned short* __restrict__ Og) {
    __shared__ char Ks[16384];
    __shared__ char Vs[16384];
    const int tid = threadIdx.x, lane = tid & 63, w = tid >> 6;
    const int g = lane >> 4, lr = lane & 15;
    const int qt = 15 - (blockIdx.x >> 5);                      // LPT: big first
    const int bh = (blockIdx.x & 7) * 4 + ((blockIdx.x >> 3) & 3);  // 4 heads/XCD
    const int b = bh >> 4, h = bh & (H_ - 1);
    const size_t base = (size_t)bh * S_ * HD_;
    const float SCL = 0.08838834764831845f * 1.4426950408889634f;  // 1/sqrt(d)*log2e

    auto stage = [&](int t) {
        const size_t tb = base + (size_t)t * 8192 + w * 2048 + (size_t)lane * 8;
        char* kd = Ks + w * 4096;
        char* vd = Vs + w * 4096;
        gll16(Kt + tb, kd);               gll16(Kt + tb + 512, kd + 1024);
        gll16(Kt + tb + 1024, kd + 2048); gll16(Kt + tb + 1536, kd + 3072);
        gll16(Vt + tb, vd);               gll16(Vt + tb + 512, vd + 1024);
        gll16(Vt + tb + 1024, vd + 2048); gll16(Vt + tb + 1536, vd + 3072);
    };

    const int q0 = qt * 128;
    const int qrA = q0 + w * 16 + lr, qrB = qrA + 64;

    bf16x8 qfA[4], qfB[4];
    #pragma unroll
    for (int st = 0; st < 4; ++st) {
        bf16x8 ta = *(const bf16x8*)(Qg + base + (size_t)qrA * HD_ + st * 32 + g * 8);
        bf16x8 tb2 = *(const bf16x8*)(Qg + base + (size_t)qrB * HD_ + st * 32 + g * 8);
        #pragma unroll
        for (int j = 0; j < 8; ++j) {
            ta[j] = (short)f2bf(bf2f((unsigned short)ta[j]) * SCL);
            tb2[j] = (short)f2bf(bf2f((unsigned short)tb2[j]) * SCL);
        }
        qfA[st] = ta; qfB[st] = tb2;
    }

    float mA = -1e30f, lA = 0.0f, mB = -1e30f, lB = 0.0f;
    f32x4 accA[8] = {}, accB[8] = {};
    const int nt = 2 * qt + 2;

    stage(0);

    for (int t = 0; t < nt; ++t) {
        __syncthreads();  // staging drained & visible
        const bool actA = (t < nt - 1);

        f32x4 sA[4] = {}, sB[4] = {};
        __builtin_amdgcn_s_setprio(1);
        #pragma unroll
        for (int f = 0; f < 4; ++f) {
            const int row = f * 16 + lr;
            const int sw = (row & 7) << 4;
            #pragma unroll
            for (int st = 0; st < 4; ++st) {
                bf16x8 kf = *(const bf16x8*)(Ks + row * 256 + ((st * 64 + g * 16) ^ sw));
                if (actA) sA[f] = MFMA_K32(kf, qfA[st], sA[f]);
                sB[f] = MFMA_K32(kf, qfB[st], sB[f]);
            }
        }
        __builtin_amdgcn_s_setprio(0);

        if (t == nt - 2) {  // group-A diagonal tile (kv base = q0)
            #pragma unroll
            for (int f = 0; f < 4; ++f)
                #pragma unroll
                for (int rg = 0; rg < 4; ++rg)
                    if (q0 + 32 * (f >> 1) + 8 * g + 4 * (f & 1) + rg > qrA)
                        sA[f][rg] = -1e30f;
        }
        if (t == nt - 1) {  // group-B diagonal tile (kv base = q0+64)
            #pragma unroll
            for (int f = 0; f < 4; ++f)
                #pragma unroll
                for (int rg = 0; rg < 4; ++rg)
                    if (q0 + 64 + 32 * (f >> 1) + 8 * g + 4 * (f & 1) + rg > qrB)
                        sB[f][rg] = -1e30f;
        }

        bf16x8 pAlo, pAhi, pBlo, pBhi;
        auto softmax_step = [&](f32x4* sf, float& m_r, float& l_r, f32x4* accO,
                                bf16x8& plo, bf16x8& phi) {
            float pm = -1e30f;
            #pragma unroll
            for (int f = 0; f < 4; ++f)
                #pragma unroll
                for (int rg = 0; rg < 4; ++rg) pm = fmaxf(pm, sf[f][rg]);
            pm = fmaxf(pm, __shfl_xor(pm, 16));
            pm = fmaxf(pm, __shfl_xor(pm, 32));
            if (!__all(pm <= m_r + 8.0f)) {  // defer-max: rescale only on growth
                const float mnew = fmaxf(m_r, pm);
                const float corr = exp2f(m_r - mnew);
                m_r = mnew;
                float cj[4];
                #pragma unroll
                for (int j = 0; j < 4; ++j) cj[j] = __shfl(corr, g * 4 + j);
                #pragma unroll
                for (int db = 0; db < 8; ++db) {
                    accO[db][0] *= cj[0]; accO[db][1] *= cj[1];
                    accO[db][2] *= cj[2]; accO[db][3] *= cj[3];
                }
                l_r *= corr;
            }
            float p[16], ls = 0.0f;
            #pragma unroll
            for (int f = 0; f < 4; ++f)
                #pragma unroll
                for (int rg = 0; rg < 4; ++rg) {
                    float pv = exp2f(sf[f][rg] - m_r);
                    p[f * 4 + rg] = pv;
                    ls += pv;
                }
            union { bf16x8 v; unsigned int u[4]; } lo2, hi2;
            #pragma unroll
            for (int i = 0; i < 4; ++i) {
                asm("v_cvt_pk_bf16_f32 %0, %1, %2"
                    : "=v"(lo2.u[i]) : "v"(p[2 * i]), "v"(p[2 * i + 1]));
                asm("v_cvt_pk_bf16_f32 %0, %1, %2"
                    : "=v"(hi2.u[i]) : "v"(p[8 + 2 * i]), "v"(p[9 + 2 * i]));
            }
            plo = lo2.v; phi = hi2.v;
            ls += __shfl_xor(ls, 16);
            ls += __shfl_xor(ls, 32);
            l_r += ls;
        };
        if (actA) softmax_step(sA, mA, lA, accA, pAlo, pAhi);
        softmax_step(sB, mB, lB, accB, pBlo, pBhi);

        __builtin_amdgcn_s_setprio(1);
        #pragma unroll
        for (int db = 0; db < 8; ++db) {
            const int d = db * 16 + lr;
            bf16x8 vlo = *(const bf16x8*)(Vs + d * 128 + ((g ^ (d & 7)) << 4));
            bf16x8 vhi = *(const bf16x8*)(Vs + d * 128 + (((4 + g) ^ (d & 7)) << 4));
            if (actA) {
                accA[db] = MFMA_K32(pAlo, vlo, accA[db]);
                accA[db] = MFMA_K32(pAhi, vhi, accA[db]);
            }
            accB[db] = MFMA_K32(pBlo, vlo, accB[db]);
            accB[db] = MFMA_K32(pBhi, vhi, accB[db]);
        }
        __builtin_amdgcn_s_setprio(0);

        if (t + 1 < nt) {
            __syncthreads();  // all reads of this tile done before overwrite
            stage(t + 1);
        }
    }

    // epilogues
    {
        float lj[4];
        #pragma unroll
        for (int j = 0; j < 4; ++j) lj[j] = __shfl(lA, g * 4 + j);
        #pragma unroll
        for (int j = 0; j < 4; ++j) {
            const int qq = q0 + w * 16 + g * 4 + j;
            const float inv = 1.0f / lj[j];
            unsigned short* dst = Og + ((size_t)(b * S_ + qq)) * D_ + h * HD_;
            #pragma unroll
            for (int db = 0; db < 8; ++db)
                dst[db * 16 + lr] = f2bf(accA[db][j] * inv);
        }
        #pragma unroll
        for (int j = 0; j < 4; ++j) lj[j] = __shfl(lB, g * 4 + j);
        #pragma unroll
        for (int j = 0; j < 4; ++j) {
            const int qq = q0 + 64 + w * 16 + g * 4 + j;
            const float inv = 1.0f / lj[j];
            unsigned short* dst = Og + ((size_t)(b * S_ + qq)) * D_ + h * HD_;
            #pragma unroll
            for (int db = 0; db < 8; ++db)
                dst[db * 16 + lr] = f2bf(accB[db][j] * inv);
        }
    }
}

extern "C" void kernel_launch(void* const* d_in, const int* in_sizes, int n_in,
                              void* d_out, int out_size, void* d_ws, size_t ws_size,
                              hipStream_t stream) {
    const float* q  = (const float*)d_in[0];
    const float* k  = (const float*)d_in[1];
    const float* v  = (const float*)d_in[2];
    const float* wq = (const float*)d_in[3];
    const float* wk = (const float*)d_in[4];
    const float* wv = (const float*)d_in[5];
    const float* wo = (const float*)d_in[6];

    unsigned short* ws   = (unsigned short*)d_ws;
    unsigned short* wqb  = ws;
    unsigned short* wkb  = wqb + (size_t)D_ * D_;
    unsigned short* wvb  = wkb + (size_t)D_ * D_;
    unsigned short* wob  = wvb + (size_t)D_ * D_;
    unsigned short* xq   = wob + (size_t)D_ * D_;
    unsigned short* xk   = xq + (size_t)B_ * S_ * D_;
    unsigned short* xv   = xk + (size_t)B_ * S_ * D_;
    unsigned short* slot = xv + (size_t)B_ * S_ * D_;  // staging, then attn out

    cvt_w4<<<dim3(4096, 4), 256, 0, stream>>>(
        (const float4*)wq, (ushort4*)wqb, (const float4*)wk, (ushort4*)wkb,
        (const float4*)wv, (ushort4*)wvb, (const float4*)wo, (ushort4*)wob);

    cvt_in<<<8192, 256, 0, stream>>>((const float4*)q, (ushort4*)slot);
    gemm_xwt<0><<<512, 256, 0, stream>>>(slot, wqb, xq);
    cvt_in<<<8192, 256, 0, stream>>>((const float4*)k, (ushort4*)slot);
    gemm_xwt<1><<<512, 256, 0, stream>>>(slot, wkb, xk);
    cvt_in<<<8192, 256, 0, stream>>>((const float4*)v, (ushort4*)slot);
    gemm_xwt<2><<<512, 256, 0, stream>>>(slot, wvb, xv);

    attn_fwd<<<512, 256, 0, stream>>>(xq, xk, xv, slot);

    gemm_xwt<3><<<512, 256, 0, stream>>>(slot, wob, d_out);
}

// Round 7
// 344.363 us; speedup vs baseline: 1.1529x; 1.1529x over previous
//
#include <hip/hip_runtime.h>
#include <hip/hip_bf16.h>

#define B_ 2
#define S_ 2048
#define D_ 2048
#define H_ 16
#define HD_ 128

typedef __attribute__((ext_vector_type(4))) float f32x4;
typedef __attribute__((ext_vector_type(8))) short bf16x8;

static __device__ __forceinline__ unsigned short f2bf(float f) {
    unsigned int u = __float_as_uint(f);
    u += 0x7fffu + ((u >> 16) & 1u);
    return (unsigned short)(u >> 16);
}
static __device__ __forceinline__ float bf2f(unsigned short h) {
    return __uint_as_float(((unsigned int)h) << 16);
}

#define MFMA_K32(a, b, c) __builtin_amdgcn_mfma_f32_16x16x32_bf16(a, b, c, 0, 0, 0)

// async global->LDS, 16B per lane. LDS dest is wave-uniform base; HW adds lane*16.
static __device__ __forceinline__ void gll16(const void* g, void* l) {
    __builtin_amdgcn_global_load_lds((const __attribute__((address_space(1))) void*)g,
                                     (__attribute__((address_space(3))) void*)l,
                                     16, 0, 0);
}

// ---------------- fp32 -> bf16 converters ----------------
__global__ void cvt_in(const float4* __restrict__ src, ushort4* __restrict__ dst) {
    int i = blockIdx.x * 256 + threadIdx.x;
    float4 v = src[i];
    ushort4 o;
    o.x = f2bf(v.x); o.y = f2bf(v.y); o.z = f2bf(v.z); o.w = f2bf(v.w);
    dst[i] = o;
}

__global__ void cvt_w4(const float4* __restrict__ s0, ushort4* __restrict__ d0,
                       const float4* __restrict__ s1, ushort4* __restrict__ d1,
                       const float4* __restrict__ s2, ushort4* __restrict__ d2,
                       const float4* __restrict__ s3, ushort4* __restrict__ d3) {
    const float4* s; ushort4* d;
    switch (blockIdx.y) {
        case 0: s = s0; d = d0; break;
        case 1: s = s1; d = d1; break;
        case 2: s = s2; d = d2; break;
        default: s = s3; d = d3; break;
    }
    int i = blockIdx.x * 256 + threadIdx.x;
    float4 v = s[i];
    ushort4 o;
    o.x = f2bf(v.x); o.y = f2bf(v.y); o.z = f2bf(v.z); o.w = f2bf(v.w);
    d[i] = o;
}

// ---------------- GEMM: C[m][n] = sum_k A[m][k] * W[n][k] ----------------
// A bf16 [4096,2048] row-major, W bf16 [2048,2048] row-major.
// Double-buffered LDS, ONE barrier per K-step, pure global_load_lds staging.
// OUT_MODE: 0=bf16 headed [B,H,S,HD]; 1=K attn tiles; 2=V attn tiles; 3=fp32 [M,N].
template<int OUT_MODE>
__global__ __launch_bounds__(256) void gemm_xwt(
        const unsigned short* __restrict__ A,
        const unsigned short* __restrict__ W,
        void* __restrict__ C) {
    constexpr int K = D_;
    __shared__ unsigned short As[2][128 * 32];
    __shared__ unsigned short Ws[2][128 * 32];
    const int tid = threadIdx.x, lane = tid & 63, wid = tid >> 6;
    const int wy = wid >> 1, wx = wid & 1;
    const int g = lane >> 4, lr = lane & 15;
    const int swz = (blockIdx.x & 7) * 64 + (blockIdx.x >> 3);  // XCD swizzle (512%8==0)
    const int bm = (swz & 31) * 128;
    const int bn = (swz >> 5) * 128;

    const int r0 = (wid * 128 + lane) >> 2, c0 = (lane & 3) * 8;  // gll16 chunk map
    const int r1 = r0 + 16;

    f32x4 acc[4][4] = {};

    auto stage = [&](int k0, int nb) {
        gll16(A + (size_t)(bm + r0) * K + k0 + c0, (char*)&As[nb][0] + wid * 2048);
        gll16(A + (size_t)(bm + r1) * K + k0 + c0, (char*)&As[nb][0] + wid * 2048 + 1024);
        gll16(W + (size_t)(bn + r0) * K + k0 + c0, (char*)&Ws[nb][0] + wid * 2048);
        gll16(W + (size_t)(bn + r1) * K + k0 + c0, (char*)&Ws[nb][0] + wid * 2048 + 1024);
    };

    stage(0, 0);  // prologue
    int cur = 0;

    for (int k0 = 0; k0 < K; k0 += 32) {
        __syncthreads();  // drains prefetch: buf[cur] ready; buf[cur^1] free
        if (k0 + 32 < K) stage(k0 + 32, cur ^ 1);
        bf16x8 af[4], wf[4];
        #pragma unroll
        for (int i = 0; i < 4; ++i)
            af[i] = *(const bf16x8*)((const char*)&As[cur][0] + (wy * 64 + i * 16 + lr) * 64 + g * 16);
        #pragma unroll
        for (int i = 0; i < 4; ++i)
            wf[i] = *(const bf16x8*)((const char*)&Ws[cur][0] + (wx * 64 + i * 16 + lr) * 64 + g * 16);
        #pragma unroll
        for (int mi = 0; mi < 4; ++mi)
            #pragma unroll
            for (int ni = 0; ni < 4; ++ni)
                acc[mi][ni] = MFMA_K32(af[mi], wf[ni], acc[mi][ni]);
        cur ^= 1;
    }

    #pragma unroll
    for (int mi = 0; mi < 4; ++mi) {
        #pragma unroll
        for (int ni = 0; ni < 4; ++ni) {
            const int n = bn + wx * 64 + ni * 16 + lr;
            const int m0 = bm + wy * 64 + mi * 16 + g * 4;
            if constexpr (OUT_MODE == 0) {
                #pragma unroll
                for (int rg = 0; rg < 4; ++rg) {
                    int m = m0 + rg;
                    int bb = m >> 11, s = m & (S_ - 1);
                    int hh = n >> 7, dd = n & (HD_ - 1);
                    ((unsigned short*)C)[(((size_t)(bb * H_ + hh) * S_) + s) * HD_ + dd] =
                        f2bf(acc[mi][ni][rg]);
                }
            } else if constexpr (OUT_MODE == 1) {
                #pragma unroll
                for (int rg = 0; rg < 4; ++rg) {
                    int m = m0 + rg;
                    int bb = m >> 11, s = m & (S_ - 1);
                    int hh = n >> 7, dd = n & (HD_ - 1);
                    int vr = s & 63;
                    int pr = (vr & 3) | (((vr >> 3) & 3) << 2) | (((vr >> 2) & 1) << 4) | (vr & 32);
                    size_t eo = ((size_t)(bb * H_ + hh) << 18) + ((size_t)(s >> 6) << 13)
                              + pr * 128 + (((((unsigned)dd) << 1) ^ ((pr & 7) << 4)) >> 1);
                    ((unsigned short*)C)[eo] = f2bf(acc[mi][ni][rg]);
                }
            } else if constexpr (OUT_MODE == 2) {
                int bb = m0 >> 11, s0 = m0 & (S_ - 1);
                int hh = n >> 7, dd = n & (HD_ - 1);
                int ch = ((s0 & 63) >> 3) ^ (dd & 7);
                size_t eo = ((size_t)(bb * H_ + hh) << 18) + ((size_t)(s0 >> 6) << 13)
                          + dd * 64 + (ch << 3) + (s0 & 7);
                ushort4 pk;
                pk.x = f2bf(acc[mi][ni][0]); pk.y = f2bf(acc[mi][ni][1]);
                pk.z = f2bf(acc[mi][ni][2]); pk.w = f2bf(acc[mi][ni][3]);
                *(ushort4*)&((unsigned short*)C)[eo] = pk;
            } else {
                #pragma unroll
                for (int rg = 0; rg < 4; ++rg)
                    ((float*)C)[(size_t)(m0 + rg) * D_ + n] = acc[mi][ni][rg];
            }
        }
    }
}

// ---------------- causal flash attention ----------------
// 512 blocks, one 128-row q-tile each; 4 waves, each wave owns TWO 16-row
// q-groups (A and A+64) so each K/V LDS read feeds 2 MFMAs. Double-buffered
// 64KB LDS, ONE barrier per tile (staging overlaps compute). 2 blocks/CU.
// Mapping: hi=i>>8, j=i&255, bh=j&31 (bh%8==XCD -> 4 heads/XCD, K+V=4MB=L2),
// qt = hi ? p : 15-p  -> per-XCD work exactly uniform, heavy tiles first.
__global__ __launch_bounds__(256) void attn_fwd(
        const unsigned short* __restrict__ Qg,
        const unsigned short* __restrict__ Kt,
        const unsigned short* __restrict__ Vt,
        unsigned short* __restrict__ Og) {
    __shared__ char Ks[2][16384];
    __shared__ char Vs[2][16384];
    const int tid = threadIdx.x, lane = tid & 63, w = tid >> 6;
    const int g = lane >> 4, lr = lane & 15;
    const int i = blockIdx.x;
    const int hi = i >> 8, j = i & 255;
    const int bh = j & 31;
    const int p = j >> 5;
    const int qt = hi ? p : 15 - p;
    const int b = bh >> 4, h = bh & (H_ - 1);
    const size_t base = (size_t)bh * S_ * HD_;
    const float SCL = 0.08838834764831845f * 1.4426950408889634f;  // 1/sqrt(d)*log2e

    auto stage = [&](int t, int nb) {
        const size_t tb = base + (size_t)t * 8192 + w * 2048 + (size_t)lane * 8;
        char* kd = &Ks[nb][0] + w * 4096;
        char* vd = &Vs[nb][0] + w * 4096;
        gll16(Kt + tb, kd);               gll16(Kt + tb + 512, kd + 1024);
        gll16(Kt + tb + 1024, kd + 2048); gll16(Kt + tb + 1536, kd + 3072);
        gll16(Vt + tb, vd);               gll16(Vt + tb + 512, vd + 1024);
        gll16(Vt + tb + 1024, vd + 2048); gll16(Vt + tb + 1536, vd + 3072);
    };

    const int q0 = qt * 128;
    const int qrA = q0 + w * 16 + lr, qrB = qrA + 64;

    bf16x8 qfA[4], qfB[4];
    #pragma unroll
    for (int st = 0; st < 4; ++st) {
        bf16x8 ta = *(const bf16x8*)(Qg + base + (size_t)qrA * HD_ + st * 32 + g * 8);
        bf16x8 tb2 = *(const bf16x8*)(Qg + base + (size_t)qrB * HD_ + st * 32 + g * 8);
        #pragma unroll
        for (int jj = 0; jj < 8; ++jj) {
            ta[jj] = (short)f2bf(bf2f((unsigned short)ta[jj]) * SCL);
            tb2[jj] = (short)f2bf(bf2f((unsigned short)tb2[jj]) * SCL);
        }
        qfA[st] = ta; qfB[st] = tb2;
    }

    float mA = -1e30f, lA = 0.0f, mB = -1e30f, lB = 0.0f;
    f32x4 accA[8] = {}, accB[8] = {};
    const int nt = 2 * qt + 2;

    stage(0, 0);
    int cur = 0;

    for (int t = 0; t < nt; ++t) {
        __syncthreads();  // drains prefetch; tile t ready in buf[cur]
        if (t + 1 < nt) stage(t + 1, cur ^ 1);
        const char* Kb = &Ks[cur][0];
        const char* Vb = &Vs[cur][0];
        const bool actA = (t < nt - 1);  // last tile fully masked for group A

        f32x4 sA[4] = {}, sB[4] = {};
        __builtin_amdgcn_s_setprio(1);
        #pragma unroll
        for (int f = 0; f < 4; ++f) {
            const int row = f * 16 + lr;
            const int sw = (row & 7) << 4;
            #pragma unroll
            for (int st = 0; st < 4; ++st) {
                bf16x8 kf = *(const bf16x8*)(Kb + row * 256 + ((st * 64 + g * 16) ^ sw));
                if (actA) sA[f] = MFMA_K32(kf, qfA[st], sA[f]);
                sB[f] = MFMA_K32(kf, qfB[st], sB[f]);
            }
        }
        __builtin_amdgcn_s_setprio(0);

        if (t == nt - 2) {  // group-A diagonal tile (kv base = q0)
            #pragma unroll
            for (int f = 0; f < 4; ++f)
                #pragma unroll
                for (int rg = 0; rg < 4; ++rg)
                    if (q0 + 32 * (f >> 1) + 8 * g + 4 * (f & 1) + rg > qrA)
                        sA[f][rg] = -1e30f;
        }
        if (t == nt - 1) {  // group-B diagonal tile (kv base = q0+64)
            #pragma unroll
            for (int f = 0; f < 4; ++f)
                #pragma unroll
                for (int rg = 0; rg < 4; ++rg)
                    if (q0 + 64 + 32 * (f >> 1) + 8 * g + 4 * (f & 1) + rg > qrB)
                        sB[f][rg] = -1e30f;
        }

        bf16x8 pAlo, pAhi, pBlo, pBhi;
        auto softmax_step = [&](f32x4* sf, float& m_r, float& l_r, f32x4* accO,
                                bf16x8& plo, bf16x8& phi) {
            float pm = -1e30f;
            #pragma unroll
            for (int f = 0; f < 4; ++f)
                #pragma unroll
                for (int rg = 0; rg < 4; ++rg) pm = fmaxf(pm, sf[f][rg]);
            pm = fmaxf(pm, __shfl_xor(pm, 16));
            pm = fmaxf(pm, __shfl_xor(pm, 32));
            if (!__all(pm <= m_r + 8.0f)) {  // defer-max: rescale only on growth
                const float mnew = fmaxf(m_r, pm);
                const float corr = exp2f(m_r - mnew);
                m_r = mnew;
                float cj[4];
                #pragma unroll
                for (int jj = 0; jj < 4; ++jj) cj[jj] = __shfl(corr, g * 4 + jj);
                #pragma unroll
                for (int db = 0; db < 8; ++db) {
                    accO[db][0] *= cj[0]; accO[db][1] *= cj[1];
                    accO[db][2] *= cj[2]; accO[db][3] *= cj[3];
                }
                l_r *= corr;
            }
            float ls = 0.0f;
            #pragma unroll
            for (int f = 0; f < 2; ++f)
                #pragma unroll
                for (int rg = 0; rg < 4; ++rg) {
                    float pv = exp2f(sf[f][rg] - m_r);
                    ls += pv;
                    plo[f * 4 + rg] = (short)f2bf(pv);
                }
            #pragma unroll
            for (int f = 0; f < 2; ++f)
                #pragma unroll
                for (int rg = 0; rg < 4; ++rg) {
                    float pv = exp2f(sf[2 + f][rg] - m_r);
                    ls += pv;
                    phi[f * 4 + rg] = (short)f2bf(pv);
                }
            ls += __shfl_xor(ls, 16);
            ls += __shfl_xor(ls, 32);
            l_r += ls;
        };
        if (actA) softmax_step(sA, mA, lA, accA, pAlo, pAhi);
        softmax_step(sB, mB, lB, accB, pBlo, pBhi);

        __builtin_amdgcn_s_setprio(1);
        #pragma unroll
        for (int db = 0; db < 8; ++db) {
            const int d = db * 16 + lr;
            bf16x8 vlo = *(const bf16x8*)(Vb + d * 128 + ((g ^ (d & 7)) << 4));
            bf16x8 vhi = *(const bf16x8*)(Vb + d * 128 + (((4 + g) ^ (d & 7)) << 4));
            if (actA) {
                accA[db] = MFMA_K32(pAlo, vlo, accA[db]);
                accA[db] = MFMA_K32(pAhi, vhi, accA[db]);
            }
            accB[db] = MFMA_K32(pBlo, vlo, accB[db]);
            accB[db] = MFMA_K32(pBhi, vhi, accB[db]);
        }
        __builtin_amdgcn_s_setprio(0);
        cur ^= 1;
    }

    // epilogues
    {
        float lj[4];
        #pragma unroll
        for (int jj = 0; jj < 4; ++jj) lj[jj] = __shfl(lA, g * 4 + jj);
        #pragma unroll
        for (int jj = 0; jj < 4; ++jj) {
            const int qq = q0 + w * 16 + g * 4 + jj;
            const float inv = 1.0f / lj[jj];
            unsigned short* dst = Og + ((size_t)(b * S_ + qq)) * D_ + h * HD_;
            #pragma unroll
            for (int db = 0; db < 8; ++db)
                dst[db * 16 + lr] = f2bf(accA[db][jj] * inv);
        }
        #pragma unroll
        for (int jj = 0; jj < 4; ++jj) lj[jj] = __shfl(lB, g * 4 + jj);
        #pragma unroll
        for (int jj = 0; jj < 4; ++jj) {
            const int qq = q0 + 64 + w * 16 + g * 4 + jj;
            const float inv = 1.0f / lj[jj];
            unsigned short* dst = Og + ((size_t)(b * S_ + qq)) * D_ + h * HD_;
            #pragma unroll
            for (int db = 0; db < 8; ++db)
                dst[db * 16 + lr] = f2bf(accB[db][jj] * inv);
        }
    }
}

extern "C" void kernel_launch(void* const* d_in, const int* in_sizes, int n_in,
                              void* d_out, int out_size, void* d_ws, size_t ws_size,
                              hipStream_t stream) {
    const float* q  = (const float*)d_in[0];
    const float* k  = (const float*)d_in[1];
    const float* v  = (const float*)d_in[2];
    const float* wq = (const float*)d_in[3];
    const float* wk = (const float*)d_in[4];
    const float* wv = (const float*)d_in[5];
    const float* wo = (const float*)d_in[6];

    unsigned short* ws   = (unsigned short*)d_ws;
    unsigned short* wqb  = ws;
    unsigned short* wkb  = wqb + (size_t)D_ * D_;
    unsigned short* wvb  = wkb + (size_t)D_ * D_;
    unsigned short* wob  = wvb + (size_t)D_ * D_;
    unsigned short* xq   = wob + (size_t)D_ * D_;
    unsigned short* xk   = xq + (size_t)B_ * S_ * D_;
    unsigned short* xv   = xk + (size_t)B_ * S_ * D_;
    unsigned short* slot = xv + (size_t)B_ * S_ * D_;  // staging, then attn out

    cvt_w4<<<dim3(4096, 4), 256, 0, stream>>>(
        (const float4*)wq, (ushort4*)wqb, (const float4*)wk, (ushort4*)wkb,
        (const float4*)wv, (ushort4*)wvb, (const float4*)wo, (ushort4*)wob);

    cvt_in<<<8192, 256, 0, stream>>>((const float4*)q, (ushort4*)slot);
    gemm_xwt<0><<<512, 256, 0, stream>>>(slot, wqb, xq);
    cvt_in<<<8192, 256, 0, stream>>>((const float4*)k, (ushort4*)slot);
    gemm_xwt<1><<<512, 256, 0, stream>>>(slot, wkb, xk);
    cvt_in<<<8192, 256, 0, stream>>>((const float4*)v, (ushort4*)slot);
    gemm_xwt<2><<<512, 256, 0, stream>>>(slot, wvb, xv);

    attn_fwd<<<512, 256, 0, stream>>>(xq, xk, xv, slot);

    gemm_xwt<3><<<512, 256, 0, stream>>>(slot, wob, d_out);
}